// Round 1
// baseline (1852.100 us; speedup 1.0000x reference)
//
#include <hip/hip_runtime.h>
#include <hip/hip_bf16.h>
#include <math.h>

// ---------------- constants ----------------
#define WTOT 16810     // 2 batches * mper (41*41*5 = 8405)
#define MPER 8405

// meta layout (ints), invfreq floats at M_INVF
#define M_NKEPT 0
#define M_NWIN0 1      // 1,2,3
#define M_NWIN1 4      // 4,5,6
#define M_IS64  7
#define M_OFEAT 8
#define M_OCOOR 9
#define M_OBUF0 10     // 10,11,12
#define M_OMASK0 13    // 13,14,15
#define M_OBUF1 16     // 16,17,18
#define M_OMASK1 19    // 19,20,21
#define M_TOTAL 22
#define M_INVF 32      // 32 floats

__device__ __forceinline__ int level_of(int c) {
    if (c < 16) return 0;
    if (c < 32) return 1;
    if (c < 100000) return 2;
    return -1;
}
__device__ __forceinline__ int target_of(int lvl) {
    return (lvl == 0) ? 16 : ((lvl == 1) ? 32 : ((lvl == 2) ? 48 : 0));
}
__device__ __forceinline__ int tokens_of(int lvl) {
    return (lvl == 0) ? 16 : ((lvl == 1) ? 32 : 48);
}

// ---------------- scan helpers ----------------
__device__ __forceinline__ int wave_incl_scan(int v) {
#pragma unroll
    for (int o = 1; o < 64; o <<= 1) {
        int t = __shfl_up(v, o, 64);
        if ((int)(threadIdx.x & 63) >= o) v += t;
    }
    return v;
}

// inclusive scan across a 1024-thread block; *total = block sum
__device__ __forceinline__ int block_incl_scan_1024(int v, int* wsums, int* total) {
    int lane = threadIdx.x & 63, wid = threadIdx.x >> 6;
    int iv = wave_incl_scan(v);
    if (lane == 63) wsums[wid] = iv;
    __syncthreads();
    if (wid == 0) {
        int s = (lane < 16) ? wsums[lane] : 0;
        s = wave_incl_scan(s);
        if (lane < 16) wsums[lane] = s;
    }
    __syncthreads();
    int add = (wid > 0) ? wsums[wid - 1] : 0;
    int incl = iv + add;
    *total = wsums[15];
    __syncthreads();   // protect wsums for reuse
    return incl;
}

// ---------------- kernels ----------------

// detect whether coords are stored as int64 (high words all zero) or int32
__global__ void k_detect(const int* coors_i32, int* meta) {
    if (blockIdx.x == 0 && threadIdx.x == 0) {
        int nz = 0;
        for (int j = 0; j < 64; j++) nz += (coors_i32[2 * j + 1] != 0);
        meta[M_IS64] = (nz == 0) ? 1 : 0;
    }
}

__global__ void k_wincoords(const void* coors_raw, int N,
                            int* bwi0, int* bwi1, int* ciw0, int* ciw1,
                            int* keepf, int* counts0, const int* meta) {
    int i = blockIdx.x * blockDim.x + threadIdx.x;
    if (i >= N) return;
    int is64 = meta[M_IS64];
    int b, z, y, x;
    if (is64) {
        const long long* c = (const long long*)coors_raw;
        long long o = 4LL * i;
        b = (int)c[o]; z = (int)c[o + 1]; y = (int)c[o + 2]; x = (int)c[o + 3];
    } else {
        const int* c = (const int*)coors_raw;
        b = c[4 * i]; z = c[4 * i + 1]; y = c[4 * i + 2]; x = c[4 * i + 3];
    }
    {   // shift = false: shx=10, shy=10, shz=4
        int scx = x + 10, scy = y + 10, scz = z + 4;
        int wcx = scx / 10, wcy = scy / 10, wcz = scz >> 2;
        int w = b * MPER + wcx * 205 + wcy * 5 + wcz;
        bwi0[i] = w;
        ciw0[i] = (scz & 3) | ((scy % 10) << 8) | ((scx % 10) << 16);
        atomicAdd(&counts0[w], 1);
    }
    {   // shift = true: shx=5, shy=5, shz=2
        int scx = x + 5, scy = y + 5, scz = z + 2;
        int wcx = scx / 10, wcy = scy / 10, wcz = scz >> 2;
        int w = b * MPER + wcx * 205 + wcy * 5 + wcz;
        bwi1[i] = w;
        ciw1[i] = (scz & 3) | ((scy % 10) << 8) | ((scx % 10) << 16);
    }
    keepf[i] = 0;
}

// single-block chunked exclusive scan; dst (and optional dst2) get exclusive
// prefix; optional total_out gets grand total. Safe for src==dst.
__global__ __launch_bounds__(1024) void k_scan_small(const int* src, int* dst, int* dst2,
                                                     int* total_out, int n) {
    __shared__ int wsums[16];
    __shared__ int running;
    if (threadIdx.x == 0) running = 0;
    __syncthreads();
    for (int base = 0; base < n; base += 1024) {
        int i = base + threadIdx.x;
        int v = (i < n) ? src[i] : 0;
        int total;
        int incl = block_incl_scan_1024(v, wsums, &total);
        int run = running;
        if (i < n) {
            int e = run + incl - v;
            dst[i] = e;
            if (dst2) dst2[i] = e;
        }
        __syncthreads();
        if (threadIdx.x == 0) running = run + total;
        __syncthreads();
    }
    if (threadIdx.x == 0 && total_out) *total_out = running;
}

__global__ void k_scatter(const int* bwi, const int* pred, int* cursor, int* sorted, int N) {
    int i = blockIdx.x * blockDim.x + threadIdx.x;
    if (i >= N) return;
    if (pred && !pred[i]) return;
    int p = atomicAdd(&cursor[bwi[i]], 1);
    sorted[p] = i;
}

// per-window: sort segment ascending (stable ranks), emit level + keep flag
__global__ void k_sortrank(const int* counts, const int* starts, int* sorted,
                           int* lvlArr, int* keepArr, int W) {
    int w = blockIdx.x * blockDim.x + threadIdx.x;
    if (w >= W) return;
    int c = counts[w];
    if (c <= 0) return;
    int s = starts[w];
    for (int a = 1; a < c; a++) {
        int v = sorted[s + a];
        int b2 = a - 1;
        while (b2 >= 0) {
            int u = sorted[s + b2];
            if (u <= v) break;
            sorted[s + b2 + 1] = u;
            b2--;
        }
        sorted[s + b2 + 1] = v;
    }
    int lvl = level_of(c);
    int tgt = target_of(lvl);
    for (int p = 0; p < c; p++) {
        int i = sorted[s + p];
        lvlArr[i] = lvl;
        keepArr[i] = (p < tgt) ? 1 : 0;
    }
}

__global__ void k_hist_pred(const int* bwi, const int* pred, int* counts, int N) {
    int i = blockIdx.x * blockDim.x + threadIdx.x;
    if (i >= N) return;
    if (pred[i]) atomicAdd(&counts[bwi[i]], 1);
}

__global__ void k_fcount(const int* bwi0, const int* bwi1, const int* keepf,
                         int* f0, int* f1, int N) {
    int i = blockIdx.x * blockDim.x + threadIdx.x;
    if (i >= N) return;
    if (keepf[i]) {
        atomicAdd(&f0[bwi0[i]], 1);
        atomicAdd(&f1[bwi1[i]], 1);
    }
}

// rank among final-kept voxels inside each window, in original-index order
__global__ void k_final_inner(const int* counts, const int* starts, const int* sorted,
                              const int* keepf, int* innerF, int W) {
    int w = blockIdx.x * blockDim.x + threadIdx.x;
    if (w >= W) return;
    int c = counts[w];
    if (c <= 0) return;
    int s = starts[w];
    int r = 0;
    for (int p = 0; p < c; p++) {
        int i = sorted[s + p];
        if (keepf[i]) innerF[i] = r++;
    }
}

// conti[w] = index of w among active same-level windows (ascending id);
// nwin_out[3] = per-level active window counts.
__global__ __launch_bounds__(1024) void k_conti(const int* counts, const int* fcount,
                                                int* conti, int* nwin_out, int n) {
    __shared__ int wsums[16];
    __shared__ int run3[3];
    if (threadIdx.x < 3) run3[threadIdx.x] = 0;
    __syncthreads();
    for (int base = 0; base < n; base += 1024) {
        int i = base + threadIdx.x;
        int c = (i < n) ? counts[i] : 0;
        int f = (i < n) ? fcount[i] : 0;
        int lvl = level_of(c);
        int act = (c > 0 && f > 0 && lvl >= 0) ? 1 : 0;
        int packed = act ? (1 << (11 * lvl)) : 0;   // 3 x 11-bit fields, chunk sums <= 1024
        int total;
        int incl = block_incl_scan_1024(packed, wsums, &total);
        int excl = incl - packed;
        int r0 = run3[0], r1 = run3[1], r2 = run3[2];
        if (i < n) {
            int e;
            if (lvl == 0) e = r0 + (excl & 2047);
            else if (lvl == 1) e = r1 + ((excl >> 11) & 2047);
            else e = r2 + ((excl >> 22) & 2047);
            conti[i] = e;
        }
        __syncthreads();
        if (threadIdx.x == 0) {
            run3[0] = r0 + (total & 2047);
            run3[1] = r1 + ((total >> 11) & 2047);
            run3[2] = r2 + ((total >> 22) & 2047);
        }
        __syncthreads();
    }
    if (threadIdx.x < 3) nwin_out[threadIdx.x] = run3[threadIdx.x];
}

__global__ __launch_bounds__(1024) void k_scan_blocks(const int* flags, int* pos,
                                                      int* bsums, int n) {
    __shared__ int wsums[16];
    int gid = blockIdx.x * 1024 + threadIdx.x;
    int v = (gid < n) ? flags[gid] : 0;
    int total;
    int incl = block_incl_scan_1024(v, wsums, &total);
    if (gid < n) pos[gid] = incl - v;
    if (threadIdx.x == 0) bsums[blockIdx.x] = total;
}

__global__ void k_scan_add(const int* flags, int* pos, const int* bsums, int* idxarr, int n) {
    int gid = blockIdx.x * blockDim.x + threadIdx.x;
    if (gid >= n) return;
    int p = pos[gid] + bsums[gid >> 10];
    pos[gid] = p;
    if (flags[gid]) idxarr[p] = gid;
}

__global__ void k_meta(int* meta) {
    if (blockIdx.x || threadIdx.x) return;
    const int T[3] = {16, 32, 48};
    long long nk = meta[M_NKEPT];
    long long o = nk * 192;
    meta[M_OFEAT] = 0;
    meta[M_OCOOR] = (int)o;
    o += nk * 4;
    for (int d = 0; d < 3; d++) { meta[M_OBUF0 + d] = (int)o; o += (long long)meta[M_NWIN0 + d] * T[d] * 192; }
    for (int d = 0; d < 3; d++) { meta[M_OMASK0 + d] = (int)o; o += (long long)meta[M_NWIN0 + d] * T[d]; }
    for (int d = 0; d < 3; d++) { meta[M_OBUF1 + d] = (int)o; o += (long long)meta[M_NWIN1 + d] * T[d] * 192; }
    for (int d = 0; d < 3; d++) { meta[M_OMASK1 + d] = (int)o; o += (long long)meta[M_NWIN1 + d] * T[d]; }
    meta[M_TOTAL] = (int)o;
    float* invf = (float*)(meta + M_INVF);
    for (int kk = 0; kk < 32; kk++)
        invf[kk] = (float)exp(6.907755278982137 * (double)kk / 32.0);  // 1000^(kk/32)
}

// zeros over pe-buffer regions, ones over mask regions
__global__ void k_background(float* out, const int* meta, int out_size) {
    int zs = meta[M_OBUF0];
    int m0s = meta[M_OMASK0], m0e = meta[M_OBUF1];
    int m1s = meta[M_OMASK1];
    long long step = (long long)gridDim.x * blockDim.x;
    for (long long e = (long long)blockIdx.x * blockDim.x + threadIdx.x; e < out_size; e += step) {
        if (e < zs) continue;
        float v = ((e >= m0s && e < m0e) || e >= m1s) ? 1.0f : 0.0f;
        out[e] = v;
    }
}

// one 64-thread block per kept voxel: gather feats+coords, scatter pe rows + mask slots
__global__ void k_emit(const float* feats, const void* coors_raw, const int* meta,
                       const int* idxarr, const int* bwi0, const int* bwi1,
                       const int* ciw0, const int* ciw1,
                       const int* lvl0, const int* lvl1,
                       const int* innerF0, const int* innerF1,
                       const int* conti0, const int* conti1,
                       float* out) {
    int k = blockIdx.x;
    int nk = meta[M_NKEPT];
    if (k >= nk) return;
    int t = threadIdx.x;
    int i = idxarr[k];
    const float* invf = (const float*)(meta + M_INVF);

    // features row (192 floats = 48 float4)
    {
        const float4* src = (const float4*)(feats + (long long)i * 192);
        float4* dst = (float4*)(out + (long long)k * 192);
        if (t < 48) dst[t] = src[t];
    }
    // coords (4 values)
    if (t < 4) {
        int v;
        if (meta[M_IS64]) v = (int)((const long long*)coors_raw)[4LL * i + t];
        else v = ((const int*)coors_raw)[4 * i + t];
        out[meta[M_OCOOR] + 4 * k + t] = (float)v;
    }
    // pos-embed + mask, both shifts
#pragma unroll
    for (int s = 0; s < 2; s++) {
        int w     = s ? bwi1[i] : bwi0[i];
        int lvl   = s ? lvl1[i] : lvl0[i];
        int ciw   = s ? ciw1[i] : ciw0[i];
        int inner = s ? innerF1[i] : innerF0[i];
        int cont  = s ? conti1[w] : conti0[w];
        int T = tokens_of(lvl);
        int row = cont * T + inner;
        int bufbase = meta[(s ? M_OBUF1 : M_OBUF0) + lvl];
        int maskbase = meta[(s ? M_OMASK1 : M_OMASK0) + lvl];
        float zc = (float)(ciw & 0xff) - 2.0f;
        float yc = (float)((ciw >> 8) & 0xff) - 5.0f;
        float xc = (float)((ciw >> 16) & 0xff) - 5.0f;
        float* po = out + bufbase + (long long)row * 192;
        for (int j = t; j < 192; j += 64) {
            int sel = j >> 6;                 // 0:x 1:y 2:z
            float v = (sel == 0) ? xc : ((sel == 1) ? yc : zc);
            float f = invf[(j & 63) >> 1];
            float e = v / f;
            po[j] = (j & 1) ? cosf(e) : sinf(e);
        }
        if (t == 0) out[maskbase + row] = 0.0f;
    }
}

// ---------------- host launch ----------------
extern "C" void kernel_launch(void* const* d_in, const int* in_sizes, int n_in,
                              void* d_out, int out_size, void* d_ws, size_t ws_size,
                              hipStream_t stream) {
    const float* feats = (const float*)d_in[0];
    const void* coors = d_in[1];
    int N = in_sizes[0] / 192;

    int* I = (int*)d_ws;
    int* bwi0 = I;               int* bwi1 = bwi0 + N;
    int* ciw0 = bwi1 + N;        int* ciw1 = ciw0 + N;
    int* sorted0 = ciw1 + N;     int* sorted1 = sorted0 + N;
    int* lvl0 = sorted1 + N;     int* lvl1 = lvl0 + N;
    int* keep0 = lvl1 + N;       int* keepf = keep0 + N;
    int* innerF0 = keepf + N;    int* innerF1 = innerF0 + N;
    int* keeppos = innerF1 + N;  int* idxarr = keeppos + N;
    int* counts0 = idxarr + N;
    int* counts1 = counts0 + WTOT;
    int* fcount0 = counts1 + WTOT;
    int* fcount1 = fcount0 + WTOT;
    int* starts0 = fcount1 + WTOT;
    int* starts1 = starts0 + WTOT;
    int* cursor0 = starts1 + WTOT;
    int* cursor1 = cursor0 + WTOT;
    int* conti0 = cursor1 + WTOT;
    int* conti1 = conti0 + WTOT;
    int nb1024 = (N + 1023) / 1024;
    int* bsums = conti1 + WTOT;
    int* meta = bsums + nb1024;

    int nb256 = (N + 255) / 256;
    int wb256 = (WTOT + 255) / 256;

    // zero counts0,counts1,fcount0,fcount1 (contiguous)
    hipMemsetAsync(counts0, 0, 4 * sizeof(int) * WTOT, stream);

    k_detect<<<1, 64, 0, stream>>>((const int*)coors, meta);
    k_wincoords<<<nb256, 256, 0, stream>>>(coors, N, bwi0, bwi1, ciw0, ciw1, keepf, counts0, meta);

    // shift 0: rank + keep
    k_scan_small<<<1, 1024, 0, stream>>>(counts0, starts0, cursor0, (int*)nullptr, WTOT);
    k_scatter<<<nb256, 256, 0, stream>>>(bwi0, (const int*)nullptr, cursor0, sorted0, N);
    k_sortrank<<<wb256, 256, 0, stream>>>(counts0, starts0, sorted0, lvl0, keep0, WTOT);

    // shift 1 on kept-of-shift0
    k_hist_pred<<<nb256, 256, 0, stream>>>(bwi1, keep0, counts1, N);
    k_scan_small<<<1, 1024, 0, stream>>>(counts1, starts1, cursor1, (int*)nullptr, WTOT);
    k_scatter<<<nb256, 256, 0, stream>>>(bwi1, keep0, cursor1, sorted1, N);
    k_sortrank<<<wb256, 256, 0, stream>>>(counts1, starts1, sorted1, lvl1, keepf, WTOT);

    // final stats
    k_fcount<<<nb256, 256, 0, stream>>>(bwi0, bwi1, keepf, fcount0, fcount1, N);
    k_final_inner<<<wb256, 256, 0, stream>>>(counts0, starts0, sorted0, keepf, innerF0, WTOT);
    k_final_inner<<<wb256, 256, 0, stream>>>(counts1, starts1, sorted1, keepf, innerF1, WTOT);
    k_conti<<<1, 1024, 0, stream>>>(counts0, fcount0, conti0, meta + M_NWIN0, WTOT);
    k_conti<<<1, 1024, 0, stream>>>(counts1, fcount1, conti1, meta + M_NWIN1, WTOT);

    // compaction: idx = flatnonzero(keepf)
    k_scan_blocks<<<nb1024, 1024, 0, stream>>>(keepf, keeppos, bsums, N);
    k_scan_small<<<1, 1024, 0, stream>>>(bsums, bsums, (int*)nullptr, meta + M_NKEPT, nb1024);
    k_scan_add<<<nb256, 256, 0, stream>>>(keepf, keeppos, bsums, idxarr, N);

    // offsets + invfreq table
    k_meta<<<1, 1, 0, stream>>>(meta);

    // fill buffers (zeros) and masks (ones), then emit per-kept-voxel data
    k_background<<<4096, 256, 0, stream>>>((float*)d_out, meta, out_size);
    k_emit<<<N, 64, 0, stream>>>(feats, coors, meta, idxarr, bwi0, bwi1, ciw0, ciw1,
                                 lvl0, lvl1, innerF0, innerF1, conti0, conti1,
                                 (float*)d_out);
    (void)n_in; (void)ws_size; (void)out_size;
}

// Round 2
// 1837.239 us; speedup vs baseline: 1.0081x; 1.0081x over previous
//
#include <hip/hip_runtime.h>
#include <hip/hip_bf16.h>
#include <math.h>

// ---------------- constants ----------------
#define WTOT 16810     // 2 batches * mper (41*41*5 = 8405)
#define MPER 8405
#define MAXROWS (WTOT * 48)

// meta layout (ints), invfreq floats at M_INVF
#define M_NKEPT 0
#define M_NWIN0 1      // 1,2,3
#define M_NWIN1 4      // 4,5,6
#define M_IS64  7
#define M_OFEAT 8
#define M_OCOOR 9
#define M_OBUF0 10     // 10,11,12
#define M_OMASK0 13    // 13,14,15
#define M_OBUF1 16     // 16,17,18
#define M_OMASK1 19    // 19,20,21
#define M_TOTAL 22
#define M_INVF 32      // 32 floats

__device__ __forceinline__ int level_of(int c) {
    if (c < 16) return 0;
    if (c < 32) return 1;
    return 2;          // c < 100000 always here
}
__device__ __forceinline__ int target_of(int lvl) {
    return (lvl == 0) ? 16 : ((lvl == 1) ? 32 : 48);
}

// ---------------- scan helpers ----------------
__device__ __forceinline__ int wave_incl_scan(int v) {
#pragma unroll
    for (int o = 1; o < 64; o <<= 1) {
        int t = __shfl_up(v, o, 64);
        if ((int)(threadIdx.x & 63) >= o) v += t;
    }
    return v;
}

__device__ __forceinline__ int block_incl_scan_1024(int v, int* wsums, int* total) {
    int lane = threadIdx.x & 63, wid = threadIdx.x >> 6;
    int iv = wave_incl_scan(v);
    if (lane == 63) wsums[wid] = iv;
    __syncthreads();
    if (wid == 0) {
        int s = (lane < 16) ? wsums[lane] : 0;
        s = wave_incl_scan(s);
        if (lane < 16) wsums[lane] = s;
    }
    __syncthreads();
    int add = (wid > 0) ? wsums[wid - 1] : 0;
    int incl = iv + add;
    *total = wsums[15];
    __syncthreads();
    return incl;
}

// ---------------- kernels ----------------

__global__ void k_detect(const int* coors_i32, int* meta) {
    if (blockIdx.x == 0 && threadIdx.x == 0) {
        int nz = 0;
        for (int j = 0; j < 64; j++) nz += (coors_i32[2 * j + 1] != 0);
        meta[M_IS64] = (nz == 0) ? 1 : 0;
    }
}

// window ids + in-window coords for both shifts; per-chunk histogram of bwi0
__global__ void k_wincoords(const void* coors_raw, int N,
                            int* bwi0, int* bwi1, int* ciw0, int* ciw1,
                            int* H0, const int* meta) {
    int i = blockIdx.x * blockDim.x + threadIdx.x;
    if (i >= N) return;
    int b, z, y, x;
    if (meta[M_IS64]) {
        const long long* c = (const long long*)coors_raw;
        long long o = 4LL * i;
        b = (int)c[o]; z = (int)c[o + 1]; y = (int)c[o + 2]; x = (int)c[o + 3];
    } else {
        const int* c = (const int*)coors_raw;
        b = c[4 * i]; z = c[4 * i + 1]; y = c[4 * i + 2]; x = c[4 * i + 3];
    }
    int chunk = i >> 10;
    {   // shift=false: shx=10, shy=10, shz=4
        int scx = x + 10, scy = y + 10, scz = z + 4;
        int w = b * MPER + (scx / 10) * 205 + (scy / 10) * 5 + (scz >> 2);
        bwi0[i] = w;
        ciw0[i] = (scz & 3) | ((scy % 10) << 8) | ((scx % 10) << 16);
        atomicAdd(&H0[(long long)chunk * WTOT + w], 1);
    }
    {   // shift=true: shx=5, shy=5, shz=2
        int scx = x + 5, scy = y + 5, scz = z + 2;
        int w = b * MPER + (scx / 10) * 205 + (scy / 10) * 5 + (scz >> 2);
        bwi1[i] = w;
        ciw1[i] = (scz & 3) | ((scy % 10) << 8) | ((scx % 10) << 16);
    }
}

// per-window serial prefix over chunks (in-place exclusive); counts = total
__global__ void k_prefix(int* H, int* counts, int C) {
    int w = blockIdx.x * blockDim.x + threadIdx.x;
    if (w >= WTOT) return;
    int run = 0;
    long long idx = w;
    for (int c = 0; c < C; c++, idx += WTOT) {
        int t = H[idx];
        H[idx] = run;
        run += t;
    }
    counts[w] = run;
}

// stage1: inner rank in bwi0 (all voxels) -> keep0; histogram bwi1 over kept
__global__ __launch_bounds__(1024) void k_stage1(const int* bwi0, const int* bwi1,
        const int* counts0, const int* H0, int* H1, int* keep0, int N) {
    __shared__ alignas(16) int swin[1024];
    int c = blockIdx.x, t = threadIdx.x;
    int i = (c << 10) + t;
    int w0 = (i < N) ? bwi0[i] : -1;
    swin[t] = w0;
    __syncthreads();
    if (i >= N) return;
    int local = 0;
    int jlim = ((t >> 6) + 1) << 6;
    const int4* s4 = (const int4*)swin;
    for (int j = 0; j < jlim; j += 4) {
        int4 q = s4[j >> 2];
        local += (q.x == w0 && j + 0 < t);
        local += (q.y == w0 && j + 1 < t);
        local += (q.z == w0 && j + 2 < t);
        local += (q.w == w0 && j + 3 < t);
    }
    int inner = H0[(long long)c * WTOT + w0] + local;
    int k0 = inner < target_of(level_of(counts0[w0]));
    keep0[i] = k0;
    if (k0) atomicAdd(&H1[(long long)c * WTOT + bwi1[i]], 1);
}

// stage2: inner rank in bwi1 among keep0 -> keepf; histograms for final stage
__global__ __launch_bounds__(1024) void k_stage2(const int* bwi0, const int* bwi1,
        const int* keep0, const int* counts1k, const int* H1,
        int* HF0, int* HF1, int* keepf, int* chunkcnt, int N) {
    __shared__ alignas(16) int swin[1024];
    __shared__ int blksum;
    int c = blockIdx.x, t = threadIdx.x;
    int i = (c << 10) + t;
    int k0 = (i < N) ? keep0[i] : 0;
    int w1 = k0 ? bwi1[i] : -1;
    swin[t] = w1;
    if (t == 0) blksum = 0;
    __syncthreads();
    int kf = 0;
    if (w1 >= 0) {
        int local = 0;
        int jlim = ((t >> 6) + 1) << 6;
        const int4* s4 = (const int4*)swin;
        for (int j = 0; j < jlim; j += 4) {
            int4 q = s4[j >> 2];
            local += (q.x == w1 && j + 0 < t);
            local += (q.y == w1 && j + 1 < t);
            local += (q.z == w1 && j + 2 < t);
            local += (q.w == w1 && j + 3 < t);
        }
        int inner1 = H1[(long long)c * WTOT + w1] + local;
        kf = inner1 < target_of(level_of(counts1k[w1]));
    }
    if (i < N) keepf[i] = kf;
    if (kf) {
        atomicAdd(&HF0[(long long)c * WTOT + bwi0[i]], 1);
        atomicAdd(&HF1[(long long)c * WTOT + w1], 1);
    }
    unsigned long long b = __ballot(kf);
    if ((t & 63) == 0) atomicAdd(&blksum, __popcll(b));
    __syncthreads();
    if (t == 0) chunkcnt[c] = blksum;
}

// generic single-block chunked exclusive scan (in-place safe)
__global__ __launch_bounds__(1024) void k_scan_small(const int* src, int* dst,
                                                     int* total_out, int n) {
    __shared__ int wsums[16];
    __shared__ int running;
    if (threadIdx.x == 0) running = 0;
    __syncthreads();
    for (int base = 0; base < n; base += 1024) {
        int i = base + threadIdx.x;
        int v = (i < n) ? src[i] : 0;
        int total;
        int incl = block_incl_scan_1024(v, wsums, &total);
        int run = running;
        if (i < n) dst[i] = run + incl - v;
        __syncthreads();
        if (threadIdx.x == 0) running = run + total;
        __syncthreads();
    }
    if (threadIdx.x == 0 && total_out) *total_out = running;
}

// conti for both shifts (blockIdx.x selects shift)
__global__ __launch_bounds__(1024) void k_conti2(const int* counts0, const int* fcount0, int* conti0,
                                                 const int* counts1, const int* fcount1, int* conti1,
                                                 int* meta) {
    __shared__ int wsums[16];
    __shared__ int run3[3];
    const int* counts = blockIdx.x ? counts1 : counts0;
    const int* fcount = blockIdx.x ? fcount1 : fcount0;
    int* conti = blockIdx.x ? conti1 : conti0;
    int* nwin_out = meta + (blockIdx.x ? M_NWIN1 : M_NWIN0);
    if (threadIdx.x < 3) run3[threadIdx.x] = 0;
    __syncthreads();
    for (int base = 0; base < WTOT; base += 1024) {
        int i = base + threadIdx.x;
        int c = (i < WTOT) ? counts[i] : 0;
        int f = (i < WTOT) ? fcount[i] : 0;
        int lvl = level_of(c);
        int act = (c > 0 && f > 0) ? 1 : 0;
        int packed = act ? (1 << (11 * lvl)) : 0;
        int total;
        int incl = block_incl_scan_1024(packed, wsums, &total);
        int excl = incl - packed;
        int r0 = run3[0], r1 = run3[1], r2 = run3[2];
        if (i < WTOT) {
            int e;
            if (lvl == 0) e = r0 + (excl & 2047);
            else if (lvl == 1) e = r1 + ((excl >> 11) & 2047);
            else e = r2 + ((excl >> 22) & 2047);
            conti[i] = e;
        }
        __syncthreads();
        if (threadIdx.x == 0) {
            run3[0] = r0 + (total & 2047);
            run3[1] = r1 + ((total >> 11) & 2047);
            run3[2] = r2 + ((total >> 22) & 2047);
        }
        __syncthreads();
    }
    if (threadIdx.x < 3) nwin_out[threadIdx.x] = run3[threadIdx.x];
}

__global__ void k_meta(int* meta) {
    if (blockIdx.x || threadIdx.x) return;
    const int T[3] = {16, 32, 48};
    long long nk = meta[M_NKEPT];
    long long o = nk * 192;
    meta[M_OFEAT] = 0;
    meta[M_OCOOR] = (int)o;
    o += nk * 4;
    for (int d = 0; d < 3; d++) { meta[M_OBUF0 + d] = (int)o; o += (long long)meta[M_NWIN0 + d] * T[d] * 192; }
    for (int d = 0; d < 3; d++) { meta[M_OMASK0 + d] = (int)o; o += (long long)meta[M_NWIN0 + d] * T[d]; }
    for (int d = 0; d < 3; d++) { meta[M_OBUF1 + d] = (int)o; o += (long long)meta[M_NWIN1 + d] * T[d] * 192; }
    for (int d = 0; d < 3; d++) { meta[M_OMASK1 + d] = (int)o; o += (long long)meta[M_NWIN1 + d] * T[d]; }
    meta[M_TOTAL] = (int)o;
    float* invf = (float*)(meta + M_INVF);
    for (int kk = 0; kk < 32; kk++)
        invf[kk] = (float)exp(6.907755278982137 * (double)kk / 32.0);  // 1000^(kk/32)
}

// stage3: final inner ranks + compaction index + row->ciw scatter
__global__ __launch_bounds__(1024) void k_stage3(const int* bwi0, const int* bwi1,
        const int* ciw0, const int* ciw1, const int* keepf,
        const int* counts0, const int* counts1k,
        const int* conti0, const int* conti1,
        const int* HF0, const int* HF1, const int* chunkpref,
        const int* meta, int* idxarr, int* rowvox0, int* rowvox1, int N) {
    __shared__ alignas(16) int sw0[1024];
    __shared__ alignas(16) int sw1[1024];
    int c = blockIdx.x, t = threadIdx.x;
    int i = (c << 10) + t;
    int kf = (i < N) ? keepf[i] : 0;
    int w0 = kf ? bwi0[i] : -1;
    int w1 = kf ? bwi1[i] : -1;
    sw0[t] = w0;
    sw1[t] = w1;
    __syncthreads();
    if (!kf) return;
    int l0 = 0, l1 = 0, lk = 0;
    int jlim = ((t >> 6) + 1) << 6;
    const int4* a4 = (const int4*)sw0;
    const int4* b4 = (const int4*)sw1;
    for (int j = 0; j < jlim; j += 4) {
        int4 qa = a4[j >> 2];
        int4 qb = b4[j >> 2];
        int v0 = (j + 0 < t), v1 = (j + 1 < t), v2 = (j + 2 < t), v3 = (j + 3 < t);
        l0 += (qa.x == w0 && v0) + (qa.y == w0 && v1) + (qa.z == w0 && v2) + (qa.w == w0 && v3);
        lk += (qa.x != -1 && v0) + (qa.y != -1 && v1) + (qa.z != -1 && v2) + (qa.w != -1 && v3);
        l1 += (qb.x == w1 && v0) + (qb.y == w1 && v1) + (qb.z == w1 && v2) + (qb.w == w1 && v3);
    }
    int innerF0 = HF0[(long long)c * WTOT + w0] + l0;
    int innerF1 = HF1[(long long)c * WTOT + w1] + l1;
    int kpos = chunkpref[c] + lk;
    idxarr[kpos] = i;
    {
        int lvl = level_of(counts0[w0]);
        int T = target_of(lvl);
        int rb = (meta[M_OBUF0 + lvl] - meta[M_OBUF0]) / 192;
        rowvox0[rb + conti0[w0] * T + innerF0] = ciw0[i];
    }
    {
        int lvl = level_of(counts1k[w1]);
        int T = target_of(lvl);
        int rb = (meta[M_OBUF1 + lvl] - meta[M_OBUF1]) / 192;
        rowvox1[rb + conti1[w1] * T + innerF1] = ciw1[i];
    }
}

// gather features + coords for kept voxels (write-once, coalesced)
__global__ void k_renderA(const float* feats, const void* coors_raw, const int* meta,
                          const int* idxarr, float* out) {
    int k = blockIdx.x;
    if (k >= meta[M_NKEPT]) return;
    int t = threadIdx.x;
    int i = idxarr[k];
    const float4* src = (const float4*)(feats + (long long)i * 192);
    float4* dst = (float4*)(out + (long long)k * 192);
    if (t < 48) dst[t] = src[t];
    if (t < 4) {
        int v = meta[M_IS64] ? (int)((const long long*)coors_raw)[4LL * i + t]
                             : ((const int*)coors_raw)[4 * i + t];
        out[meta[M_OCOOR] + 4 * k + t] = (float)v;
    }
}

// write pe buffers + masks, each element exactly once, coalesced
__global__ __launch_bounds__(256) void k_renderB(const int* meta, const int* rowvox0,
                                                 const int* rowvox1, float* out) {
    __shared__ float sinvf[32];
    if (threadIdx.x < 32) sinvf[threadIdx.x] = ((const float*)(meta + M_INVF))[threadIdx.x];
    int obuf0 = meta[M_OBUF0], omask0 = meta[M_OMASK0];
    int obuf1 = meta[M_OBUF1], omask1 = meta[M_OMASK1];
    int ototal = meta[M_TOTAL];
    __syncthreads();
    long long step = (long long)gridDim.x * blockDim.x;
    for (long long e = obuf0 + (long long)blockIdx.x * blockDim.x + threadIdx.x;
         e < ototal; e += step) {
        float val;
        bool pe0 = (e < omask0);
        bool pe1 = (e >= obuf1 && e < omask1);
        if (pe0 || pe1) {
            long long rel = e - (pe1 ? obuf1 : obuf0);
            int row = (int)(rel / 192);
            int j = (int)(rel - (long long)row * 192);
            int ciw = pe1 ? rowvox1[row] : rowvox0[row];
            if (ciw < 0) val = 0.0f;
            else {
                float zc = (float)(ciw & 255) - 2.0f;
                float yc = (float)((ciw >> 8) & 255) - 5.0f;
                float xc = (float)((ciw >> 16) & 255) - 5.0f;
                int sel = j >> 6;
                float v = (sel == 0) ? xc : ((sel == 1) ? yc : zc);
                float a = v / sinvf[(j & 63) >> 1];
                val = (j & 1) ? cosf(a) : sinf(a);
            }
        } else {
            int r = (int)(e - ((e >= omask1) ? omask1 : omask0));
            int ciw = (e >= omask1) ? rowvox1[r] : rowvox0[r];
            val = (ciw < 0) ? 1.0f : 0.0f;
        }
        out[e] = val;
    }
}

// ---------------- host launch ----------------
extern "C" void kernel_launch(void* const* d_in, const int* in_sizes, int n_in,
                              void* d_out, int out_size, void* d_ws, size_t ws_size,
                              hipStream_t stream) {
    const float* feats = (const float*)d_in[0];
    const void* coors = d_in[1];
    int N = in_sizes[0] / 192;
    int C = (N + 1023) >> 10;

    int* I = (int*)d_ws;
    int* bwi0 = I;              int* bwi1 = bwi0 + N;
    int* ciw0 = bwi1 + N;       int* ciw1 = ciw0 + N;
    int* keep0 = ciw1 + N;      int* keepf = keep0 + N;
    int* idxarr = keepf + N;
    int* H0 = idxarr + N;                       // C*WTOT each, contiguous
    int* H1 = H0 + (long long)C * WTOT;
    int* HF0 = H1 + (long long)C * WTOT;
    int* HF1 = HF0 + (long long)C * WTOT;
    int* chunkcnt = HF1 + (long long)C * WTOT;  // C ints (zeroed with H block)
    int* counts0 = chunkcnt + C;
    int* counts1k = counts0 + WTOT;
    int* fcount0 = counts1k + WTOT;
    int* fcount1 = fcount0 + WTOT;
    int* conti0 = fcount1 + WTOT;
    int* conti1 = conti0 + WTOT;
    int* rowvox0 = conti1 + WTOT;
    int* rowvox1 = rowvox0 + MAXROWS;
    int* meta = rowvox1 + MAXROWS;

    int nb256 = (N + 255) / 256;
    int wb256 = (WTOT + 255) / 256;

    hipMemsetAsync(H0, 0, ((size_t)4 * C * WTOT + C) * sizeof(int), stream);
    hipMemsetAsync(rowvox0, 0xFF, (size_t)2 * MAXROWS * sizeof(int), stream);

    k_detect<<<1, 64, 0, stream>>>((const int*)coors, meta);
    k_wincoords<<<nb256, 256, 0, stream>>>(coors, N, bwi0, bwi1, ciw0, ciw1, H0, meta);

    k_prefix<<<wb256, 256, 0, stream>>>(H0, counts0, C);
    k_stage1<<<C, 1024, 0, stream>>>(bwi0, bwi1, counts0, H0, H1, keep0, N);

    k_prefix<<<wb256, 256, 0, stream>>>(H1, counts1k, C);
    k_stage2<<<C, 1024, 0, stream>>>(bwi0, bwi1, keep0, counts1k, H1, HF0, HF1,
                                     keepf, chunkcnt, N);

    k_prefix<<<wb256, 256, 0, stream>>>(HF0, fcount0, C);
    k_prefix<<<wb256, 256, 0, stream>>>(HF1, fcount1, C);
    k_scan_small<<<1, 1024, 0, stream>>>(chunkcnt, chunkcnt, meta + M_NKEPT, C);
    k_conti2<<<2, 1024, 0, stream>>>(counts0, fcount0, conti0, counts1k, fcount1, conti1, meta);
    k_meta<<<1, 1, 0, stream>>>(meta);

    k_stage3<<<C, 1024, 0, stream>>>(bwi0, bwi1, ciw0, ciw1, keepf, counts0, counts1k,
                                     conti0, conti1, HF0, HF1, chunkcnt, meta,
                                     idxarr, rowvox0, rowvox1, N);

    k_renderA<<<N, 64, 0, stream>>>(feats, coors, meta, idxarr, (float*)d_out);
    k_renderB<<<2048, 256, 0, stream>>>(meta, rowvox0, rowvox1, (float*)d_out);

    (void)n_in; (void)ws_size; (void)out_size;
}